// Round 11
// baseline (56.166 us; speedup 1.0000x reference)
//
#include <hip/hip_runtime.h>
#include <stdint.h>

typedef __attribute__((ext_vector_type(8))) short short8;     // bf16x8 MFMA frag
typedef __attribute__((ext_vector_type(4))) float floatx4;
typedef __attribute__((ext_vector_type(4))) unsigned int uintx4;
typedef __attribute__((ext_vector_type(2))) unsigned int uintx2;

#define S_LEN 2048
#define NHEAD 16
#define DHEAD 64
#define KB    64
#define KPL   131072                          // fp8 K plane bytes per (b,h): 2048*64
#define VPL   262144                          // bf16 V plane bytes per (b,h)
#define VOFF  (32 * KPL)                      // 4194304
#define MOFF  (VOFF + 32 * VPL)               // 12582912 (mask frags 2 b x 4096 B)
#define POFF  (MOFF + 8192)                   // O partials: 512 slots x 32 KB (f32)
#define DOFF  (POFF + 512 * 32768)            // den partials: 512 x 512 B
#define WS_NEEDED ((size_t)DOFF + 512 * 512)
#define NEGINF (-__builtin_inff())
#define LOG2E 1.4426950408889634f
#define CSC   0.011271055f                    // 0.125*log2e/16 (Q scaled x16 in fp8)

#define GLOAD_LDS16(gp, lp) \
    __builtin_amdgcn_global_load_lds((const __attribute__((address_space(1))) unsigned int*)(gp), \
                                     (__attribute__((address_space(3))) unsigned int*)(lp), 16, 0, 0)

static __device__ __forceinline__ unsigned f2bf(float f) {
    union { float f; unsigned u; } w; w.f = f;
    return (w.u + 0x7FFFu + ((w.u >> 16) & 1u)) >> 16;
}
static __device__ __forceinline__ unsigned cvtpk(float lo, float hi) {
    unsigned r;
    asm("v_cvt_pk_bf16_f32 %0, %1, %2" : "=v"(r) : "v"(lo), "v"(hi));
    return r;
}
template <int HI>
static __device__ __forceinline__ int cvtfp8(float a, float b, int old) {
    return __builtin_amdgcn_cvt_pk_fp8_f32(a, b, old, HI);   // HI is a literal
}
static __device__ __forceinline__ floatx4 mfma16(short8 a, short8 b, floatx4 c) {
    return __builtin_amdgcn_mfma_f32_16x16x32_bf16(a, b, c, 0, 0, 0);
}
static __device__ __forceinline__ floatx4 mfma8(long a, long b, floatx4 c) {
    return __builtin_amdgcn_mfma_f32_16x16x32_fp8_fp8(a, b, c, 0, 0, 0);
}

// ---------------------------------------------------------------------------
// Prepass: K -> fp8 e4m3 raw, 64B rows, granule swizzle g ^= (r&7) on 8B units;
// V -> bf16 TRANSPOSED [d][pkey] interleaved (pad rows zeroed);
// mask -> bf16 0/1 frags in PV order (128 B per (b,tile)).
// ---------------------------------------------------------------------------
__global__ __launch_bounds__(256) void prep_kernel(
    const float* __restrict__ kg, const float* __restrict__ vg,
    const int* __restrict__ mg, char* __restrict__ ws)
{
    __shared__ unsigned short Tl[64 * 72];
    const int bid = blockIdx.x;               // 0..1023
    const int t   = bid & 31;
    const int bh  = bid >> 5;
    const int b   = bh >> 4, h = bh & 15;
    const int tid = threadIdx.x;
    char* kpre = ws + (size_t)bh * KPL;
    char* vpre = ws + VOFF + (size_t)bh * VPL;

    // K: fp8 convert + granule-swizzled store (thread -> 16B of a 64B row)
    {
        const int r  = tid >> 2;              // key row in tile
        const int c4 = tid & 3;               // 16-d chunk
        const size_t grow = (((size_t)b * S_LEN + t * 64 + r) * NHEAD + h) * DHEAD + 16 * c4;
        floatx4 f0 = *(const floatx4*)(kg + grow);
        floatx4 f1 = *(const floatx4*)(kg + grow + 4);
        floatx4 f2 = *(const floatx4*)(kg + grow + 8);
        floatx4 f3 = *(const floatx4*)(kg + grow + 12);
        int w0 = 0, w1 = 0, w2 = 0, w3 = 0;
        w0 = cvtfp8<0>(f0[0], f0[1], w0); w0 = cvtfp8<1>(f0[2], f0[3], w0);
        w1 = cvtfp8<0>(f1[0], f1[1], w1); w1 = cvtfp8<1>(f1[2], f1[3], w1);
        w2 = cvtfp8<0>(f2[0], f2[1], w2); w2 = cvtfp8<1>(f2[2], f2[3], w2);
        w3 = cvtfp8<0>(f3[0], f3[1], w3); w3 = cvtfp8<1>(f3[2], f3[3], w3);
        const int Xr = r & 7;
        char* dst = kpre + t * 4096 + r * 64 + 8 * (((2 * c4) ^ Xr) & ~1);
        *(uintx4*)dst = (Xr & 1)
            ? (uintx4){(unsigned)w2, (unsigned)w3, (unsigned)w0, (unsigned)w1}
            : (uintx4){(unsigned)w0, (unsigned)w1, (unsigned)w2, (unsigned)w3};
    }
    // V: load rows coalesced, zero pad-masked rows, transpose into LDS
    {
        const int key = tid >> 2;
        const int d0  = (tid & 3) * 16;
        const float vz = mg[(size_t)b * S_LEN + t * 64 + key] ? 1.f : 0.f;
        const size_t grow = (((size_t)b * S_LEN + t * 64 + key) * NHEAD + h) * DHEAD;
        #pragma unroll
        for (int q = 0; q < 4; ++q) {
            floatx4 f = *(const floatx4*)(vg + grow + d0 + 4 * q);
            #pragma unroll
            for (int ii = 0; ii < 4; ++ii)
                Tl[(d0 + 4 * q + ii) * 72 + key] = (unsigned short)f2bf(f[ii] * vz);
        }
    }
    __syncthreads();
    // V out: swizzled 16B chunks, keys in interleaved storage order
    {
        const int d  = tid >> 2;
        const int c0 = (tid & 3) * 32;
        const int Xv = (d & 7) << 4;
        #pragma unroll
        for (int cc = 0; cc < 2; ++cc) {
            const int c   = c0 + 16 * cc;
            const int pp0 = (c ^ Xv) >> 1;
            const int blk = pp0 >> 5;
            const int a   = (pp0 & 31) >> 3;
            unsigned short vals[8];
            #pragma unroll
            for (int i = 0; i < 8; ++i) {
                const int key = 32 * blk + ((i < 4) ? (4 * a + i) : (16 + 4 * a + i - 4));
                vals[i] = Tl[d * 72 + key];
            }
            *(uintx4*)(vpre + t * 8192 + d * 128 + c) = *(const uintx4*)vals;
        }
    }
    // mask frags
    if (h == 0 && tid < 64) {
        const int key = tid;
        const int gg = (key >> 2) & 3, lo = key & 3;
        const int ks = key >> 5,      hi = (key >> 4) & 1;
        const unsigned short mv = mg[(size_t)b * S_LEN + t * 64 + key] ? 0x3F80 : 0;
        *(unsigned short*)(ws + MOFF + (size_t)b * 4096 + t * 128
                           + gg * 32 + ks * 16 + (4 * hi + lo) * 2) = mv;
    }
}

// ---------------------------------------------------------------------------
// Main: 128 q-rows/block, 8 waves = 4wq x 2kh, grp=2. fp8 QK^T (Q x16, scale
// via fma into exp2), bf16 PV. qb>=8 key-split into 2 chunks -> f32 partials.
// 32 KB LDS. Fixed-max softmax (-8 in exp2 fma); den via mask-MFMA.
// ---------------------------------------------------------------------------
__global__ __launch_bounds__(512, 4) void fa3_main(
    const float* __restrict__ qg, char* __restrict__ ws,
    float* __restrict__ og)
{
    __shared__ char smem[32768];
    char* Qs  = smem;                          // 8 KB fp8 [128 x 64B]
    char* KsB = smem + 8192;                   // 2 x 4 KB fp8
    char* VsB = smem + 16384;                  // 2 x 8 KB bf16

    const int tid  = threadIdx.x;
    const int bid  = blockIdx.x;
    const int gidx = bid >> 5;
    const int bh   = bid & 31;
    int qb, chunk; bool split;
    if (gidx < 16) { qb = 15 - (gidx >> 1); chunk = gidx & 1; split = true; }
    else           { qb = 7 - (gidx - 16);  chunk = 0;        split = false; }
    const int b    = bh >> 4;
    const int h    = bh & 15;
    const int w    = tid >> 6;
    const int lane = tid & 63;
    const int g    = lane >> 4;
    const int lm   = lane & 15;
    const int kh   = w >> 2;                  // key half 0/1
    const int wq   = w & 3;                   // q sub-block [32wq, 32wq+32)
    const char* kpre = ws + (size_t)bh * KPL;
    const char* vpre = ws + VOFF + (size_t)bh * VPL;
    const char* mgf  = ws + MOFF + (size_t)b * 4096;
    const int nkt = (qb == 0) ? 2 : (2 * qb + 2);
    int kt0 = 0, kt1 = nkt;
    if (split) { const int hh = nkt >> 1; kt0 = chunk ? hh : 0; kt1 = chunk ? nkt : hh; }

    // stage first tile (K: 256 thr x 16B = 4KB; V: 512 x 16B = 8KB)
    if (tid < 256) GLOAD_LDS16(kpre + (size_t)kt0 * 4096 + tid * 16, KsB + tid * 16);
    GLOAD_LDS16(vpre + (size_t)kt0 * 8192 + tid * 16, VsB + tid * 16);

    // stage Q: L2-normalize, x16, fp8, granule-swizzled
    {
        const int r  = tid >> 2;              // q-row 0..127
        const int q0 = tid & 3;
        const float* src = qg + (((size_t)b * S_LEN + (size_t)qb * 128 + r) * NHEAD + h) * DHEAD + q0 * 16;
        floatx4 f0 = *(const floatx4*)(src + 0);
        floatx4 f1 = *(const floatx4*)(src + 4);
        floatx4 f2 = *(const floatx4*)(src + 8);
        floatx4 f3 = *(const floatx4*)(src + 12);
        float ssq = 0.f;
        #pragma unroll
        for (int i = 0; i < 4; ++i)
            ssq += f0[i]*f0[i] + f1[i]*f1[i] + f2[i]*f2[i] + f3[i]*f3[i];
        ssq += __shfl_xor(ssq, 1);
        ssq += __shfl_xor(ssq, 2);
        const float sc = 16.0f / fmaxf(sqrtf(ssq), 1e-12f);
        int w0 = 0, w1 = 0, w2 = 0, w3 = 0;
        w0 = cvtfp8<0>(f0[0]*sc, f0[1]*sc, w0); w0 = cvtfp8<1>(f0[2]*sc, f0[3]*sc, w0);
        w1 = cvtfp8<0>(f1[0]*sc, f1[1]*sc, w1); w1 = cvtfp8<1>(f1[2]*sc, f1[3]*sc, w1);
        w2 = cvtfp8<0>(f2[0]*sc, f2[1]*sc, w2); w2 = cvtfp8<1>(f2[2]*sc, f2[3]*sc, w2);
        w3 = cvtfp8<0>(f3[0]*sc, f3[1]*sc, w3); w3 = cvtfp8<1>(f3[2]*sc, f3[3]*sc, w3);
        const int Xr = r & 7;
        char* qp = Qs + r * 64 + 8 * (((2 * q0) ^ Xr) & ~1);
        *(uintx4*)qp = (Xr & 1)
            ? (uintx4){(unsigned)w2, (unsigned)w3, (unsigned)w0, (unsigned)w1}
            : (uintx4){(unsigned)w0, (unsigned)w1, (unsigned)w2, (unsigned)w3};
    }
    asm volatile("s_waitcnt vmcnt(0)" ::: "memory");
    __syncthreads();

    const int Xl8  = (lm & 7) << 3;
    const int Xl16 = (lm & 7) << 4;
    // per-lane fp8 Q frags (contiguous 8-byte map; permutation cancels in QK)
    long qf8[2][2];
    #pragma unroll
    for (int grp = 0; grp < 2; ++grp) {
        const char* base = Qs + (wq * 32 + grp * 16 + lm) * 64;
        #pragma unroll
        for (int ksd = 0; ksd < 2; ++ksd)
            qf8[grp][ksd] = *(const long*)(base + ((32 * ksd + 8 * g) ^ Xl8));
    }

    floatx4 oacc[2][4];
    floatx4 dacc[2];
    #pragma unroll
    for (int grp = 0; grp < 2; ++grp) {
        dacc[grp] = (floatx4){0.f,0.f,0.f,0.f};
        #pragma unroll
        for (int nt = 0; nt < 4; ++nt) oacc[grp][nt] = (floatx4){0.f,0.f,0.f,0.f};
    }
    floatx4 ZERO4 = (floatx4){0.f,0.f,0.f,0.f};
    asm volatile("" : "+v"(ZERO4));
    const int qgl0 = qb * 128 + wq * 32 + lm;

    int cur = 0;
    for (int kt = kt0; kt < kt1; ++kt) {
        if (kt + 1 < kt1) {
            if (tid < 256)
                GLOAD_LDS16(kpre + (size_t)(kt + 1) * 4096 + tid * 16,
                            KsB + (cur ^ 1) * 4096 + tid * 16);
            GLOAD_LDS16(vpre + (size_t)(kt + 1) * 8192 + tid * 16,
                        VsB + (cur ^ 1) * 8192 + tid * 16);
        }
        const short8 mf = *(const short8*)(mgf + kt * 128 + g * 32 + kh * 16);

        // ---- fp8 swapped QK^T on this wave's 32 keys; C-init = 0 ----
        floatx4 st[2][2];
        const char* kbase = KsB + cur * 4096 + kh * 2048 + lm * 64;
        __builtin_amdgcn_s_setprio(1);
        #pragma unroll
        for (int mt = 0; mt < 2; ++mt) {
            long kf = *(const long*)(kbase + mt * 1024 + ((8 * g) ^ Xl8));
            st[0][mt] = mfma8(kf, qf8[0][0], ZERO4);
            st[1][mt] = mfma8(kf, qf8[1][0], ZERO4);
        }
        #pragma unroll
        for (int mt = 0; mt < 2; ++mt) {
            long kf = *(const long*)(kbase + mt * 1024 + ((32 + 8 * g) ^ Xl8));
            st[0][mt] = mfma8(kf, qf8[0][1], st[0][mt]);
            st[1][mt] = mfma8(kf, qf8[1][1], st[1][mt]);
        }
        __builtin_amdgcn_s_setprio(0);

        // ---- causal (diagonal tiles kt in {2qb,2qb+1}, qb>=1) ----
        if ((qb >= 1) && (kt >= 2 * qb)) {
            #pragma unroll
            for (int mt = 0; mt < 2; ++mt)
                #pragma unroll
                for (int j = 0; j < 4; ++j) {
                    const int kgl = kt * KB + kh * 32 + mt * 16 + 4 * g + j;
                    if (kgl > qgl0)      st[0][mt][j] = -1e6f;
                    if (kgl > qgl0 + 16) st[1][mt][j] = -1e6f;
                }
        }

        // ---- p = exp2(st*CSC - 8); pack bf16; den-MFMA + PV-MFMA ----
        short8 pa[2];
        #pragma unroll
        for (int grp = 0; grp < 2; ++grp) {
            float p[8];
            #pragma unroll
            for (int mt = 0; mt < 2; ++mt)
                #pragma unroll
                for (int j = 0; j < 4; ++j)
                    p[mt * 4 + j] = exp2f(fmaf(st[grp][mt][j], CSC, -8.0f));
            union { short8 s; uintx4 u; } pu;
            pu.u = (uintx4){ cvtpk(p[0], p[1]), cvtpk(p[2], p[3]),
                             cvtpk(p[4], p[5]), cvtpk(p[6], p[7]) };
            pa[grp] = pu.s;
        }
        __builtin_amdgcn_s_setprio(1);
        dacc[0] = mfma16(pa[0], mf, dacc[0]);
        dacc[1] = mfma16(pa[1], mf, dacc[1]);
        {
            const char* vbase = VsB + cur * 8192 + lm * 128;
            #pragma unroll
            for (int nt = 0; nt < 4; ++nt) {
                short8 vf = *(const short8*)(vbase + nt * 2048 + ((64 * kh + 16 * g) ^ Xl16));
                oacc[0][nt] = mfma16(pa[0], vf, oacc[0][nt]);
                oacc[1][nt] = mfma16(pa[1], vf, oacc[1][nt]);
            }
        }
        __builtin_amdgcn_s_setprio(0);

        asm volatile("s_waitcnt vmcnt(0)" ::: "memory");
        __syncthreads();
        cur ^= 1;
    }

    // ---- combine key halves (rbuf = whole 32KB smem; K/V/Q dead) ----
    floatx4* rbuf = (floatx4*)smem;
    float*   dbuf = (float*)smem;
    if (kh == 1) {
        #pragma unroll
        for (int grp = 0; grp < 2; ++grp)
            #pragma unroll
            for (int nt = 0; nt < 4; ++nt)
                rbuf[((grp * 4 + nt) * 4 + wq) * 64 + lane] = oacc[grp][nt];
    }
    __syncthreads();
    if (kh == 0) {
        #pragma unroll
        for (int grp = 0; grp < 2; ++grp)
            #pragma unroll
            for (int nt = 0; nt < 4; ++nt)
                oacc[grp][nt] += rbuf[((grp * 4 + nt) * 4 + wq) * 64 + lane];
    }
    __syncthreads();
    if (kh == 1 && lm == 0) {
        #pragma unroll
        for (int grp = 0; grp < 2; ++grp)
            #pragma unroll
            for (int j = 0; j < 4; ++j)
                dbuf[wq * 32 + grp * 16 + 4 * g + j] = dacc[grp][j];
    }
    __syncthreads();
    if (kh == 0) {
        if (!split) {
            #pragma unroll
            for (int grp = 0; grp < 2; ++grp)
                #pragma unroll
                for (int j = 0; j < 4; ++j) {
                    const int rl = wq * 32 + grp * 16 + 4 * g + j;
                    const float invj = 1.0f / (dacc[grp][j] + dbuf[rl]);
                    float* dst = og + (((size_t)b * S_LEN + qb * 128 + rl) * NHEAD + h) * DHEAD + lm;
                    #pragma unroll
                    for (int nt = 0; nt < 4; ++nt) dst[nt * 16] = oacc[grp][nt][j] * invj;
                }
        } else {
            const int s = ((qb - 8) * 32 + bh) * 2 + chunk;
            float* po = (float*)(ws + POFF + (size_t)s * 32768);
            float* pd = (float*)(ws + DOFF + (size_t)s * 512);
            #pragma unroll
            for (int grp = 0; grp < 2; ++grp)
                #pragma unroll
                for (int j = 0; j < 4; ++j) {
                    const int rl = wq * 32 + grp * 16 + 4 * g + j;
                    #pragma unroll
                    for (int nt = 0; nt < 4; ++nt)
                        po[rl * 64 + nt * 16 + lm] = oacc[grp][nt][j];
                    if (lm == 0) pd[rl] = dacc[grp][j] + dbuf[rl];
                }
        }
    }
}

// ---------------------------------------------------------------------------
// Combine (qb 8..15): out = (P0+P1)/(D0+D1).
// ---------------------------------------------------------------------------
__global__ __launch_bounds__(256) void fa3_combine(
    const char* __restrict__ ws, float* __restrict__ og)
{
    const int i0  = (blockIdx.x * 256 + threadIdx.x) * 8;
    const int d   = i0 & 63;
    const int row = (i0 >> 6) & 127;
    const int bh  = (i0 >> 13) & 31;
    const int qbi = i0 >> 18;                 // 0..7 -> qb = 8+qbi
    const int b   = bh >> 4, h = bh & 15;
    const int s0  = (qbi * 32 + bh) * 2;
    const float* p0 = (const float*)(ws + POFF + (size_t)s0 * 32768) + row * 64 + d;
    const float* p1 = (const float*)(ws + POFF + (size_t)(s0 + 1) * 32768) + row * 64 + d;
    const float den = ((const float*)(ws + DOFF + (size_t)s0 * 512))[row]
                    + ((const float*)(ws + DOFF + (size_t)(s0 + 1) * 512))[row];
    const float inv = 1.0f / den;
    floatx4 a0 = *(const floatx4*)p0, a1 = *(const floatx4*)(p0 + 4);
    floatx4 b0 = *(const floatx4*)p1, b1 = *(const floatx4*)(p1 + 4);
    floatx4 o0, o1;
    #pragma unroll
    for (int i = 0; i < 4; ++i) { o0[i] = (a0[i] + b0[i]) * inv; o1[i] = (a1[i] + b1[i]) * inv; }
    float* dst = og + (((size_t)b * S_LEN + (8 + qbi) * 128 + row) * NHEAD + h) * DHEAD + d;
    *(floatx4*)dst       = o0;
    *(floatx4*)(dst + 4) = o1;
}

// ---------------------------------------------------------------------------
// Fallback (round-2 kernel, known-good) if ws_size is too small.
// ---------------------------------------------------------------------------
__global__ __launch_bounds__(512) void fa3_fallback(
    const float* __restrict__ qg, const float* __restrict__ kg,
    const float* __restrict__ vg, const int* __restrict__ mg,
    float* __restrict__ og)
{
    __shared__ unsigned short Qs[128 * DHEAD];
    __shared__ unsigned short Ks2[KB * DHEAD];
    __shared__ unsigned short Vt[DHEAD * KB];
    __shared__ float Ms[KB];

    const int tid  = threadIdx.x;
    const int bid  = blockIdx.x;
    const int qb   = 15 - (bid >> 5);
    const int bh   = bid & 31;
    const int b    = bh >> 4;
    const int h    = bh & 15;
    const int w    = tid >> 6;
    const int lane = tid & 63;
    const int g    = lane >> 4;
    const int lm   = lane & 15;

    {
        const int r  = tid >> 2;
        const int q0 = tid & 3;
        const float* src = qg + (((size_t)b * S_LEN + (size_t)qb * 128 + r) * NHEAD + h) * DHEAD + q0 * 16;
        floatx4 f0 = *(const floatx4*)(src + 0);
        floatx4 f1 = *(const floatx4*)(src + 4);
        floatx4 f2 = *(const floatx4*)(src + 8);
        floatx4 f3 = *(const floatx4*)(src + 12);
        float ssq = 0.f;
        #pragma unroll
        for (int i = 0; i < 4; ++i)
            ssq += f0[i]*f0[i] + f1[i]*f1[i] + f2[i]*f2[i] + f3[i]*f3[i];
        ssq += __shfl_xor(ssq, 1);
        ssq += __shfl_xor(ssq, 2);
        const float sc = 0.125f / fmaxf(sqrtf(ssq), 1e-12f);
        float fv[16];
        #pragma unroll
        for (int i = 0; i < 4; ++i) { fv[i]=f0[i]; fv[4+i]=f1[i]; fv[8+i]=f2[i]; fv[12+i]=f3[i]; }
        unsigned pk[8];
        #pragma unroll
        for (int i = 0; i < 8; ++i)
            pk[i] = f2bf(fv[2*i]*sc) | (f2bf(fv[2*i+1]*sc) << 16);
        const int X = (r & 7) << 4;
        char* qp = (char*)Qs + r * 128;
        *(uintx4*)(qp + ((32*q0)      ^ X)) = (uintx4){pk[0],pk[1],pk[2],pk[3]};
        *(uintx4*)(qp + ((32*q0 + 16) ^ X)) = (uintx4){pk[4],pk[5],pk[6],pk[7]};
    }
    __syncthreads();

    short8 qf[2];
    {
        const int row = w * 16 + lm;
        const int X = (row & 7) << 4;
        const char* base = (const char*)Qs + row * 128;
        #pragma unroll
        for (int ks = 0; ks < 2; ++ks) {
            union { short8 s; uintx2 u[2]; } u;
            u.u[0] = *(const uintx2*)(base + ((64*ks + 8*g)      ^ X));
            u.u[1] = *(const uintx2*)(base + ((64*ks + 8*g + 32) ^ X));
            qf[ks] = u.s;
        }
    }

    floatx4 oacc[4];
    #pragma unroll
    for (int nt = 0; nt < 4; ++nt) oacc[nt] = (floatx4){0.f,0.f,0.f,0.f};
    float mrun = NEGINF, lrun = 0.f;
    const int q_glob = qb * 128 + w * 16 + lm;
    const int nkt = (qb == 0) ? 2 : (2 * qb + 2);

    for (int kt = 0; kt < nkt; ++kt) {
        const int kb0 = kt * KB;
        {
            const int r = tid >> 3;
            const int o = tid & 7;
            const size_t goff = (((size_t)b * S_LEN + kb0 + r) * NHEAD + h) * DHEAD + o * 8;
            floatx4 a0 = *(const floatx4*)(kg + goff);
            floatx4 a1 = *(const floatx4*)(kg + goff + 4);
            floatx4 c0 = *(const floatx4*)(vg + goff);
            floatx4 c1 = *(const floatx4*)(vg + goff + 4);
            uintx4 kw = (uintx4){ f2bf(a0[0]) | (f2bf(a0[1])<<16),
                                  f2bf(a0[2]) | (f2bf(a0[3])<<16),
                                  f2bf(a1[0]) | (f2bf(a1[1])<<16),
                                  f2bf(a1[2]) | (f2bf(a1[3])<<16) };
            *(uintx4*)((char*)Ks2 + r*128 + ((16*o) ^ ((r & 7) << 4))) = kw;
            float cv[8];
            #pragma unroll
            for (int i = 0; i < 4; ++i) { cv[i] = c0[i]; cv[4+i] = c1[i]; }
            #pragma unroll
            for (int i = 0; i < 8; ++i) {
                const int d = 8*o + i;
                Vt[d*64 + (r ^ (((i ^ o) & 7) << 3))] = (unsigned short)f2bf(cv[i]);
            }
            if (tid < KB) Ms[tid] = mg[(size_t)b * S_LEN + kb0 + tid] ? 0.f : NEGINF;
        }
        __syncthreads();

        floatx4 st[4];
        #pragma unroll
        for (int mt = 0; mt < 4; ++mt) st[mt] = (floatx4){0.f,0.f,0.f,0.f};
        #pragma unroll
        for (int ks = 0; ks < 2; ++ks) {
            #pragma unroll
            for (int mt = 0; mt < 4; ++mt) {
                const int row = mt * 16 + lm;
                const int X = (row & 7) << 4;
                const char* base = (const char*)Ks2 + row * 128;
                union { short8 s; uintx2 u[2]; } u;
                u.u[0] = *(const uintx2*)(base + ((64*ks + 8*g)      ^ X));
                u.u[1] = *(const uintx2*)(base + ((64*ks + 8*g + 32) ^ X));
                st[mt] = mfma16(u.s, qf[ks], st[mt]);
            }
        }

        const bool diag = (qb > 0) && (kt >= 2 * qb);
        float sv[16];
        #pragma unroll
        for (int mt = 0; mt < 4; ++mt) {
            #pragma unroll
            for (int j = 0; j < 4; ++j) {
                const int kl = mt * 16 + 4 * g + j;
                float s = st[mt][j] + Ms[kl];
                if (diag && (kb0 + kl > q_glob)) s = NEGINF;
                sv[mt * 4 + j] = s;
            }
        }

        float rmax = sv[0];
        #pragma unroll
        for (int i = 1; i < 16; ++i) rmax = fmaxf(rmax, sv[i]);
        rmax = fmaxf(rmax, __shfl_xor(rmax, 16));
        rmax = fmaxf(rmax, __shfl_xor(rmax, 32));
        const float mnew = fmaxf(mrun, rmax);
        const float cf = __expf(mrun - mnew);
        float p[16], psum = 0.f;
        #pragma unroll
        for (int i = 0; i < 16; ++i) { p[i] = __expf(sv[i] - mnew); psum += p[i]; }
        psum += __shfl_xor(psum, 16);
        psum += __shfl_xor(psum, 32);
        lrun = lrun * cf + psum;
        mrun = mnew;

        float cj[4];
        #pragma unroll
        for (int j = 0; j < 4; ++j) cj[j] = __shfl(cf, 20 * g + j);
        #pragma unroll
        for (int nt = 0; nt < 4; ++nt)
            #pragma unroll
            for (int j = 0; j < 4; ++j) oacc[nt][j] *= cj[j];

        short8 pa[2];
        #pragma unroll
        for (int ks = 0; ks < 2; ++ks)
            #pragma unroll
            for (int i = 0; i < 8; ++i)
                pa[ks][i] = (short)f2bf(p[(2*ks + (i>>2))*4 + (i&3)]);

        #pragma unroll
        for (int nt = 0; nt < 4; ++nt) {
            const int d = 16 * nt + lm;
            const int xz = (((d & 7) ^ ((d >> 3) & 7)) & 7) << 4;
            const char* vb = (const char*)Vt + d * 128;
            #pragma unroll
            for (int ks = 0; ks < 2; ++ks) {
                union { short8 s; uintx2 u[2]; } vu;
                vu.u[0] = *(const uintx2*)(vb + ((64*ks + 8*g)      ^ xz));
                vu.u[1] = *(const uintx2*)(vb + ((64*ks + 8*g + 32) ^ xz));
                oacc[nt] = mfma16(pa[ks], vu.s, oacc[nt]);
            }
        }
        __syncthreads();
    }

    const float inv = 1.0f / lrun;
    #pragma unroll
    for (int j = 0; j < 4; ++j) {
        const float invj = __shfl(inv, 20 * g + j);
        const int row = qb * 128 + w * 16 + 4 * g + j;
        float* dst = og + (((size_t)b * S_LEN + row) * NHEAD + h) * DHEAD + lm;
        #pragma unroll
        for (int nt = 0; nt < 4; ++nt) dst[nt * 16] = oacc[nt][j] * invj;
    }
}

extern "C" void kernel_launch(void* const* d_in, const int* in_sizes, int n_in,
                              void* d_out, int out_size, void* d_ws, size_t ws_size,
                              hipStream_t stream)
{
    const float* q = (const float*)d_in[0];
    const float* k = (const float*)d_in[1];
    const float* v = (const float*)d_in[2];
    const int*   m = (const int*)d_in[3];
    float* out = (float*)d_out;
    (void)in_sizes; (void)n_in; (void)out_size;
    if (ws_size >= WS_NEEDED) {
        prep_kernel<<<dim3(1024), dim3(256), 0, stream>>>(k, v, m, (char*)d_ws);
        fa3_main<<<dim3(768), dim3(512), 0, stream>>>(q, (char*)d_ws, out);
        fa3_combine<<<dim3(1024), dim3(256), 0, stream>>>((const char*)d_ws, out);
    } else {
        fa3_fallback<<<dim3(512), dim3(512), 0, stream>>>(q, k, v, m, out);
    }
}

// Round 12
// 52.875 us; speedup vs baseline: 1.0622x; 1.0622x over previous
//
#include <hip/hip_runtime.h>
#include <stdint.h>

typedef __attribute__((ext_vector_type(8))) short short8;     // bf16x8 MFMA frag
typedef __attribute__((ext_vector_type(4))) float floatx4;
typedef __attribute__((ext_vector_type(4))) unsigned int uintx4;
typedef __attribute__((ext_vector_type(2))) unsigned int uintx2;
typedef unsigned long long ulong64;

#define S_LEN 2048
#define NHEAD 16
#define DHEAD 64
#define KB    64
#define KPL   131072                          // fp8 K plane bytes per (b,h): 32 tiles x 4KB
#define VPL   262144                          // bf16 V plane bytes per (b,h): 32 tiles x 8KB
#define VOFF  (32 * KPL)                      // 4194304
#define MOFF  (VOFF + 32 * VPL)               // 12582912 (mask frags 2 b x 4096 B)
#define POFF  (MOFF + 8192)                   // O partials: 512 slots x 32 KB (f32)
#define DOFF  (POFF + 512 * 32768)            // den partials: 512 x 512 B
#define WS_NEEDED ((size_t)DOFF + 512 * 512)
#define NEGINF (-__builtin_inff())
#define CSC   0.011271055f                    // 0.125*log2e/16 (Q scaled x16 in fp8)

static __device__ __forceinline__ unsigned f2bf(float f) {
    union { float f; unsigned u; } w; w.f = f;
    return (w.u + 0x7FFFu + ((w.u >> 16) & 1u)) >> 16;
}
static __device__ __forceinline__ unsigned cvtpk(float lo, float hi) {
    unsigned r;
    asm("v_cvt_pk_bf16_f32 %0, %1, %2" : "=v"(r) : "v"(lo), "v"(hi));
    return r;
}
template <int HI>
static __device__ __forceinline__ int cvtfp8(float a, float b, int old) {
    return __builtin_amdgcn_cvt_pk_fp8_f32(a, b, old, HI);
}
static __device__ __forceinline__ floatx4 mfma16(short8 a, short8 b, floatx4 c) {
    return __builtin_amdgcn_mfma_f32_16x16x32_bf16(a, b, c, 0, 0, 0);
}
static __device__ __forceinline__ floatx4 mfma8(long a, long b, floatx4 c) {
    return __builtin_amdgcn_mfma_f32_16x16x32_fp8_fp8(a, b, c, 0, 0, 0);
}

// ---------------------------------------------------------------------------
// Prepass: K -> fp8 e4m3 in FRAG-STREAM order: tile offset
//   kh*2048 + mt*1024 + ksd*512 + lane*8  holds K[key=kh*32+mt*16+(lane&15)]
//   [d = 32*ksd + 8*(lane>>4) .. +8)  -> main's K frag load is one coalesced
//   global_load_dwordx2. V -> bf16 frag-stream: kh*4096 + nt*1024 + lane*16
//   holds V^T[d=16*nt+(lane&15)][pkeys (4*kh+lane>>4)*8 .. +8) with the pkey
//   interleave folded in; pad-masked V rows zeroed. Mask -> bf16 0/1 frags.
// ---------------------------------------------------------------------------
__global__ __launch_bounds__(256) void prep_kernel(
    const float* __restrict__ kg, const float* __restrict__ vg,
    const int* __restrict__ mg, char* __restrict__ ws)
{
    __shared__ unsigned short Tl[64 * 72];
    const int bid = blockIdx.x;               // 0..1023
    const int t   = bid & 31;
    const int bh  = bid >> 5;
    const int b   = bh >> 4, h = bh & 15;
    const int tid = threadIdx.x;
    char* kpre = ws + (size_t)bh * KPL;
    char* vpre = ws + VOFF + (size_t)bh * VPL;

    // K frag-stream: 512 slots x 8B, 2 slots per thread
    #pragma unroll
    for (int r2 = 0; r2 < 2; ++r2) {
        const int ss  = tid + r2 * 256;
        const int khs = ss >> 8;
        const int mt  = (ss >> 7) & 1;
        const int ksd = (ss >> 6) & 1;
        const int ln  = ss & 63;
        const int key = khs * 32 + mt * 16 + (ln & 15);
        const int d0  = 32 * ksd + 8 * (ln >> 4);
        const float* kr = kg + (((size_t)b * S_LEN + t * 64 + key) * NHEAD + h) * DHEAD + d0;
        floatx4 f0 = *(const floatx4*)(kr);
        floatx4 f1 = *(const floatx4*)(kr + 4);
        int w0 = 0, w1 = 0;
        w0 = cvtfp8<0>(f0[0], f0[1], w0); w0 = cvtfp8<1>(f0[2], f0[3], w0);
        w1 = cvtfp8<0>(f1[0], f1[1], w1); w1 = cvtfp8<1>(f1[2], f1[3], w1);
        *(uintx2*)(kpre + t * 4096 + ss * 8) = (uintx2){(unsigned)w0, (unsigned)w1};
    }
    // V: load rows coalesced, zero pad-masked rows, transpose into LDS
    {
        const int key = tid >> 2;
        const int d0  = (tid & 3) * 16;
        const float vz = mg[(size_t)b * S_LEN + t * 64 + key] ? 1.f : 0.f;
        const size_t grow = (((size_t)b * S_LEN + t * 64 + key) * NHEAD + h) * DHEAD;
        #pragma unroll
        for (int q = 0; q < 4; ++q) {
            floatx4 f = *(const floatx4*)(vg + grow + d0 + 4 * q);
            #pragma unroll
            for (int ii = 0; ii < 4; ++ii)
                Tl[(d0 + 4 * q + ii) * 72 + key] = (unsigned short)f2bf(f[ii] * vz);
        }
    }
    __syncthreads();
    // V frag-stream: 512 slots x 16B, 2 slots per thread (pkey interleave)
    #pragma unroll
    for (int r2 = 0; r2 < 2; ++r2) {
        const int ss  = tid + r2 * 256;
        const int khs = ss >> 8;
        const int nt  = (ss >> 6) & 3;
        const int ln  = ss & 63;
        const int d   = 16 * nt + (ln & 15);
        const int pg  = 4 * khs + (ln >> 4);
        unsigned short vals[8];
        #pragma unroll
        for (int i = 0; i < 8; ++i) {
            const int p   = pg * 8 + i;
            const int blk = p >> 5;
            const int a   = (p >> 3) & 3;
            const int key = 32 * blk + ((i < 4) ? (4 * a + i) : (16 + 4 * a + i - 4));
            vals[i] = Tl[d * 72 + key];
        }
        *(uintx4*)(vpre + t * 8192 + ss * 16) = *(const uintx4*)vals;
    }
    // mask frags
    if (h == 0 && tid < 64) {
        const int key = tid;
        const int gg = (key >> 2) & 3, lo = key & 3;
        const int ks = key >> 5,      hi = (key >> 4) & 1;
        const unsigned short mv = mg[(size_t)b * S_LEN + t * 64 + key] ? 0x3F80 : 0;
        *(unsigned short*)(ws + MOFF + (size_t)b * 4096 + t * 128
                           + gg * 32 + ks * 16 + (4 * hi + lo) * 2) = mv;
    }
}

// ---------------------------------------------------------------------------
// Main: 128 q-rows/block, 8 waves = 4wq x 2kh, grp=2. NO LDS staging, NO
// barriers in the tile loop: K/V/mask frags loaded directly global->register
// (coalesced frag-stream, L2-resident). fp8 QK^T, bf16 PV, fixed-max softmax,
// den via mask-MFMA. qb>=8 key-split into 2 chunks -> f32 partials.
// ---------------------------------------------------------------------------
__global__ __launch_bounds__(512, 4) void fa3_main(
    const float* __restrict__ qg, char* __restrict__ ws,
    float* __restrict__ og)
{
    __shared__ char smem[32768];
    char* Qs = smem;                           // 8 KB fp8 Q (epilogue reuses all)

    const int tid  = threadIdx.x;
    const int bid  = blockIdx.x;
    const int gidx = bid >> 5;
    const int bh   = bid & 31;
    int qb, chunk; bool split;
    if (gidx < 16) { qb = 15 - (gidx >> 1); chunk = gidx & 1; split = true; }
    else           { qb = 7 - (gidx - 16);  chunk = 0;        split = false; }
    const int b    = bh >> 4;
    const int h    = bh & 15;
    const int w    = tid >> 6;
    const int lane = tid & 63;
    const int g    = lane >> 4;
    const int lm   = lane & 15;
    const int kh   = w >> 2;                  // key half 0/1
    const int wq   = w & 3;                   // q sub-block [32wq, 32wq+32)
    const int nkt = (qb == 0) ? 2 : (2 * qb + 2);
    int kt0 = 0, kt1 = nkt;
    if (split) { const int hh = nkt >> 1; kt0 = chunk ? hh : 0; kt1 = chunk ? nkt : hh; }

    // stage Q: L2-normalize, x16, fp8, granule-swizzled (one-time)
    {
        const int r  = tid >> 2;              // q-row 0..127
        const int q0 = tid & 3;
        const float* src = qg + (((size_t)b * S_LEN + (size_t)qb * 128 + r) * NHEAD + h) * DHEAD + q0 * 16;
        floatx4 f0 = *(const floatx4*)(src + 0);
        floatx4 f1 = *(const floatx4*)(src + 4);
        floatx4 f2 = *(const floatx4*)(src + 8);
        floatx4 f3 = *(const floatx4*)(src + 12);
        float ssq = 0.f;
        #pragma unroll
        for (int i = 0; i < 4; ++i)
            ssq += f0[i]*f0[i] + f1[i]*f1[i] + f2[i]*f2[i] + f3[i]*f3[i];
        ssq += __shfl_xor(ssq, 1);
        ssq += __shfl_xor(ssq, 2);
        const float sc = 16.0f / fmaxf(sqrtf(ssq), 1e-12f);
        int w0 = 0, w1 = 0, w2 = 0, w3 = 0;
        w0 = cvtfp8<0>(f0[0]*sc, f0[1]*sc, w0); w0 = cvtfp8<1>(f0[2]*sc, f0[3]*sc, w0);
        w1 = cvtfp8<0>(f1[0]*sc, f1[1]*sc, w1); w1 = cvtfp8<1>(f1[2]*sc, f1[3]*sc, w1);
        w2 = cvtfp8<0>(f2[0]*sc, f2[1]*sc, w2); w2 = cvtfp8<1>(f2[2]*sc, f2[3]*sc, w2);
        w3 = cvtfp8<0>(f3[0]*sc, f3[1]*sc, w3); w3 = cvtfp8<1>(f3[2]*sc, f3[3]*sc, w3);
        const int Xr = r & 7;
        char* qp = Qs + r * 64 + 8 * (((2 * q0) ^ Xr) & ~1);
        *(uintx4*)qp = (Xr & 1)
            ? (uintx4){(unsigned)w2, (unsigned)w3, (unsigned)w0, (unsigned)w1}
            : (uintx4){(unsigned)w0, (unsigned)w1, (unsigned)w2, (unsigned)w3};
    }
    __syncthreads();

    const int Xl8 = (lm & 7) << 3;
    long qf8[2][2];
    #pragma unroll
    for (int grp = 0; grp < 2; ++grp) {
        const char* base = Qs + (wq * 32 + grp * 16 + lm) * 64;
        #pragma unroll
        for (int ksd = 0; ksd < 2; ++ksd)
            qf8[grp][ksd] = *(const long*)(base + ((32 * ksd + 8 * g) ^ Xl8));
    }

    // per-lane global frag pointers (frag-stream layout -> coalesced loads)
    const char* kp = ws + (size_t)bh * KPL + (size_t)kt0 * 4096 + kh * 2048 + lane * 8;
    const char* vp = ws + VOFF + (size_t)bh * VPL + (size_t)kt0 * 8192 + kh * 4096 + lane * 16;
    const char* mp = ws + MOFF + (size_t)b * 4096 + (size_t)kt0 * 128 + g * 32 + kh * 16;

    floatx4 oacc[2][4];
    floatx4 dacc[2];
    #pragma unroll
    for (int grp = 0; grp < 2; ++grp) {
        dacc[grp] = (floatx4){0.f,0.f,0.f,0.f};
        #pragma unroll
        for (int nt = 0; nt < 4; ++nt) oacc[grp][nt] = (floatx4){0.f,0.f,0.f,0.f};
    }
    floatx4 ZERO4 = (floatx4){0.f,0.f,0.f,0.f};
    asm volatile("" : "+v"(ZERO4));
    const int qgl0 = qb * 128 + wq * 32 + lm;

    for (int kt = kt0; kt < kt1; ++kt) {
        // ---- frag loads (coalesced, L2-resident; no barriers anywhere) ----
        const ulong64 k00 = *(const ulong64*)(kp);          // mt0 ksd0
        const ulong64 k01 = *(const ulong64*)(kp + 512);    // mt0 ksd1
        const ulong64 k10 = *(const ulong64*)(kp + 1024);   // mt1 ksd0
        const ulong64 k11 = *(const ulong64*)(kp + 1536);   // mt1 ksd1
        const short8 vf0 = *(const short8*)(vp);
        const short8 vf1 = *(const short8*)(vp + 1024);
        const short8 vf2 = *(const short8*)(vp + 2048);
        const short8 vf3 = *(const short8*)(vp + 3072);
        const short8 mf  = *(const short8*)(mp);
        kp += 4096; vp += 8192; mp += 128;

        // ---- fp8 swapped QK^T; C-init = 0 ----
        floatx4 st[2][2];
        __builtin_amdgcn_s_setprio(1);
        st[0][0] = mfma8((long)k00, qf8[0][0], ZERO4);
        st[1][0] = mfma8((long)k00, qf8[1][0], ZERO4);
        st[0][1] = mfma8((long)k10, qf8[0][0], ZERO4);
        st[1][1] = mfma8((long)k10, qf8[1][0], ZERO4);
        st[0][0] = mfma8((long)k01, qf8[0][1], st[0][0]);
        st[1][0] = mfma8((long)k01, qf8[1][1], st[1][0]);
        st[0][1] = mfma8((long)k11, qf8[0][1], st[0][1]);
        st[1][1] = mfma8((long)k11, qf8[1][1], st[1][1]);
        __builtin_amdgcn_s_setprio(0);

        // ---- causal (diagonal tiles kt in {2qb,2qb+1}, qb>=1) ----
        if ((qb >= 1) && (kt >= 2 * qb)) {
            #pragma unroll
            for (int mt = 0; mt < 2; ++mt)
                #pragma unroll
                for (int j = 0; j < 4; ++j) {
                    const int kgl = kt * KB + kh * 32 + mt * 16 + 4 * g + j;
                    if (kgl > qgl0)      st[0][mt][j] = -1e6f;
                    if (kgl > qgl0 + 16) st[1][mt][j] = -1e6f;
                }
        }

        // ---- p = exp2(st*CSC - 8); pack bf16; den-MFMA + PV-MFMA ----
        short8 pa[2];
        #pragma unroll
        for (int grp = 0; grp < 2; ++grp) {
            float p[8];
            #pragma unroll
            for (int mt = 0; mt < 2; ++mt)
                #pragma unroll
                for (int j = 0; j < 4; ++j)
                    p[mt * 4 + j] = exp2f(fmaf(st[grp][mt][j], CSC, -8.0f));
            union { short8 s; uintx4 u; } pu;
            pu.u = (uintx4){ cvtpk(p[0], p[1]), cvtpk(p[2], p[3]),
                             cvtpk(p[4], p[5]), cvtpk(p[6], p[7]) };
            pa[grp] = pu.s;
        }
        __builtin_amdgcn_s_setprio(1);
        dacc[0] = mfma16(pa[0], mf, dacc[0]);
        dacc[1] = mfma16(pa[1], mf, dacc[1]);
        oacc[0][0] = mfma16(pa[0], vf0, oacc[0][0]);
        oacc[1][0] = mfma16(pa[1], vf0, oacc[1][0]);
        oacc[0][1] = mfma16(pa[0], vf1, oacc[0][1]);
        oacc[1][1] = mfma16(pa[1], vf1, oacc[1][1]);
        oacc[0][2] = mfma16(pa[0], vf2, oacc[0][2]);
        oacc[1][2] = mfma16(pa[1], vf2, oacc[1][2]);
        oacc[0][3] = mfma16(pa[0], vf3, oacc[0][3]);
        oacc[1][3] = mfma16(pa[1], vf3, oacc[1][3]);
        __builtin_amdgcn_s_setprio(0);
    }
    __syncthreads();                          // Qs dead; epilogue reuses smem

    // ---- combine key halves: kh=1 dumps to LDS, kh=0 sums ----
    floatx4* rbuf = (floatx4*)smem;
    float*   dbuf = (float*)smem;
    if (kh == 1) {
        #pragma unroll
        for (int grp = 0; grp < 2; ++grp)
            #pragma unroll
            for (int nt = 0; nt < 4; ++nt)
                rbuf[((grp * 4 + nt) * 4 + wq) * 64 + lane] = oacc[grp][nt];
    }
    __syncthreads();
    if (kh == 0) {
        #pragma unroll
        for (int grp = 0; grp < 2; ++grp)
            #pragma unroll
            for (int nt = 0; nt < 4; ++nt)
                oacc[grp][nt] += rbuf[((grp * 4 + nt) * 4 + wq) * 64 + lane];
    }
    __syncthreads();
    if (kh == 1 && lm == 0) {
        #pragma unroll
        for (int grp = 0; grp < 2; ++grp)
            #pragma unroll
            for (int j = 0; j < 4; ++j)
                dbuf[wq * 32 + grp * 16 + 4 * g + j] = dacc[grp][j];
    }
    __syncthreads();
    if (kh == 0) {
        if (!split) {
            #pragma unroll
            for (int grp = 0; grp < 2; ++grp)
                #pragma unroll
                for (int j = 0; j < 4; ++j) {
                    const int rl = wq * 32 + grp * 16 + 4 * g + j;
                    const float invj = 1.0f / (dacc[grp][j] + dbuf[rl]);
                    float* dst = og + (((size_t)b * S_LEN + qb * 128 + rl) * NHEAD + h) * DHEAD + lm;
                    #pragma unroll
                    for (int nt = 0; nt < 4; ++nt) dst[nt * 16] = oacc[grp][nt][j] * invj;
                }
        } else {
            const int s = ((qb - 8) * 32 + bh) * 2 + chunk;
            float* po = (float*)(ws + POFF + (size_t)s * 32768);
            float* pd = (float*)(ws + DOFF + (size_t)s * 512);
            #pragma unroll
            for (int grp = 0; grp < 2; ++grp)
                #pragma unroll
                for (int j = 0; j < 4; ++j) {
                    const int rl = wq * 32 + grp * 16 + 4 * g + j;
                    #pragma unroll
                    for (int nt = 0; nt < 4; ++nt)
                        po[rl * 64 + nt * 16 + lm] = oacc[grp][nt][j];
                    if (lm == 0) pd[rl] = dacc[grp][j] + dbuf[rl];
                }
        }
    }
}

// ---------------------------------------------------------------------------
// Combine (qb 8..15): out = (P0+P1)/(D0+D1).
// ---------------------------------------------------------------------------
__global__ __launch_bounds__(256) void fa3_combine(
    const char* __restrict__ ws, float* __restrict__ og)
{
    const int i0  = (blockIdx.x * 256 + threadIdx.x) * 8;
    const int d   = i0 & 63;
    const int row = (i0 >> 6) & 127;
    const int bh  = (i0 >> 13) & 31;
    const int qbi = i0 >> 18;                 // 0..7 -> qb = 8+qbi
    const int b   = bh >> 4, h = bh & 15;
    const int s0  = (qbi * 32 + bh) * 2;
    const float* p0 = (const float*)(ws + POFF + (size_t)s0 * 32768) + row * 64 + d;
    const float* p1 = (const float*)(ws + POFF + (size_t)(s0 + 1) * 32768) + row * 64 + d;
    const float den = ((const float*)(ws + DOFF + (size_t)s0 * 512))[row]
                    + ((const float*)(ws + DOFF + (size_t)(s0 + 1) * 512))[row];
    const float inv = 1.0f / den;
    floatx4 a0 = *(const floatx4*)p0, a1 = *(const floatx4*)(p0 + 4);
    floatx4 b0 = *(const floatx4*)p1, b1 = *(const floatx4*)(p1 + 4);
    floatx4 o0, o1;
    #pragma unroll
    for (int i = 0; i < 4; ++i) { o0[i] = (a0[i] + b0[i]) * inv; o1[i] = (a1[i] + b1[i]) * inv; }
    float* dst = og + (((size_t)b * S_LEN + (8 + qbi) * 128 + row) * NHEAD + h) * DHEAD + d;
    *(floatx4*)dst       = o0;
    *(floatx4*)(dst + 4) = o1;
}

// ---------------------------------------------------------------------------
// Fallback (round-2 kernel, known-good) if ws_size is too small.
// ---------------------------------------------------------------------------
__global__ __launch_bounds__(512) void fa3_fallback(
    const float* __restrict__ qg, const float* __restrict__ kg,
    const float* __restrict__ vg, const int* __restrict__ mg,
    float* __restrict__ og)
{
    __shared__ unsigned short Qs[128 * DHEAD];
    __shared__ unsigned short Ks2[KB * DHEAD];
    __shared__ unsigned short Vt[DHEAD * KB];
    __shared__ float Ms[KB];

    const int tid  = threadIdx.x;
    const int bid  = blockIdx.x;
    const int qb   = 15 - (bid >> 5);
    const int bh   = bid & 31;
    const int b    = bh >> 4;
    const int h    = bh & 15;
    const int w    = tid >> 6;
    const int lane = tid & 63;
    const int g    = lane >> 4;
    const int lm   = lane & 15;

    {
        const int r  = tid >> 2;
        const int q0 = tid & 3;
        const float* src = qg + (((size_t)b * S_LEN + (size_t)qb * 128 + r) * NHEAD + h) * DHEAD + q0 * 16;
        floatx4 f0 = *(const floatx4*)(src + 0);
        floatx4 f1 = *(const floatx4*)(src + 4);
        floatx4 f2 = *(const floatx4*)(src + 8);
        floatx4 f3 = *(const floatx4*)(src + 12);
        float ssq = 0.f;
        #pragma unroll
        for (int i = 0; i < 4; ++i)
            ssq += f0[i]*f0[i] + f1[i]*f1[i] + f2[i]*f2[i] + f3[i]*f3[i];
        ssq += __shfl_xor(ssq, 1);
        ssq += __shfl_xor(ssq, 2);
        const float sc = 0.125f / fmaxf(sqrtf(ssq), 1e-12f);
        float fv[16];
        #pragma unroll
        for (int i = 0; i < 4; ++i) { fv[i]=f0[i]; fv[4+i]=f1[i]; fv[8+i]=f2[i]; fv[12+i]=f3[i]; }
        unsigned pk[8];
        #pragma unroll
        for (int i = 0; i < 8; ++i)
            pk[i] = f2bf(fv[2*i]*sc) | (f2bf(fv[2*i+1]*sc) << 16);
        const int X = (r & 7) << 4;
        char* qp = (char*)Qs + r * 128;
        *(uintx4*)(qp + ((32*q0)      ^ X)) = (uintx4){pk[0],pk[1],pk[2],pk[3]};
        *(uintx4*)(qp + ((32*q0 + 16) ^ X)) = (uintx4){pk[4],pk[5],pk[6],pk[7]};
    }
    __syncthreads();

    short8 qf[2];
    {
        const int row = w * 16 + lm;
        const int X = (row & 7) << 4;
        const char* base = (const char*)Qs + row * 128;
        #pragma unroll
        for (int ks = 0; ks < 2; ++ks) {
            union { short8 s; uintx2 u[2]; } u;
            u.u[0] = *(const uintx2*)(base + ((64*ks + 8*g)      ^ X));
            u.u[1] = *(const uintx2*)(base + ((64*ks + 8*g + 32) ^ X));
            qf[ks] = u.s;
        }
    }

    floatx4 oacc[4];
    #pragma unroll
    for (int nt = 0; nt < 4; ++nt) oacc[nt] = (floatx4){0.f,0.f,0.f,0.f};
    float mrun = NEGINF, lrun = 0.f;
    const int q_glob = qb * 128 + w * 16 + lm;
    const int nkt = (qb == 0) ? 2 : (2 * qb + 2);

    for (int kt = 0; kt < nkt; ++kt) {
        const int kb0 = kt * KB;
        {
            const int r = tid >> 3;
            const int o = tid & 7;
            const size_t goff = (((size_t)b * S_LEN + kb0 + r) * NHEAD + h) * DHEAD + o * 8;
            floatx4 a0 = *(const floatx4*)(kg + goff);
            floatx4 a1 = *(const floatx4*)(kg + goff + 4);
            floatx4 c0 = *(const floatx4*)(vg + goff);
            floatx4 c1 = *(const floatx4*)(vg + goff + 4);
            uintx4 kw = (uintx4){ f2bf(a0[0]) | (f2bf(a0[1])<<16),
                                  f2bf(a0[2]) | (f2bf(a0[3])<<16),
                                  f2bf(a1[0]) | (f2bf(a1[1])<<16),
                                  f2bf(a1[2]) | (f2bf(a1[3])<<16) };
            *(uintx4*)((char*)Ks2 + r*128 + ((16*o) ^ ((r & 7) << 4))) = kw;
            float cv[8];
            #pragma unroll
            for (int i = 0; i < 4; ++i) { cv[i] = c0[i]; cv[4+i] = c1[i]; }
            #pragma unroll
            for (int i = 0; i < 8; ++i) {
                const int d = 8*o + i;
                Vt[d*64 + (r ^ (((i ^ o) & 7) << 3))] = (unsigned short)f2bf(cv[i]);
            }
            if (tid < KB) Ms[tid] = mg[(size_t)b * S_LEN + kb0 + tid] ? 0.f : NEGINF;
        }
        __syncthreads();

        floatx4 st[4];
        #pragma unroll
        for (int mt = 0; mt < 4; ++mt) st[mt] = (floatx4){0.f,0.f,0.f,0.f};
        #pragma unroll
        for (int ks = 0; ks < 2; ++ks) {
            #pragma unroll
            for (int mt = 0; mt < 4; ++mt) {
                const int row = mt * 16 + lm;
                const int X = (row & 7) << 4;
                const char* base = (const char*)Ks2 + row * 128;
                union { short8 s; uintx2 u[2]; } u;
                u.u[0] = *(const uintx2*)(base + ((64*ks + 8*g)      ^ X));
                u.u[1] = *(const uintx2*)(base + ((64*ks + 8*g + 32) ^ X));
                st[mt] = mfma16(u.s, qf[ks], st[mt]);
            }
        }

        const bool diag = (qb > 0) && (kt >= 2 * qb);
        float sv[16];
        #pragma unroll
        for (int mt = 0; mt < 4; ++mt) {
            #pragma unroll
            for (int j = 0; j < 4; ++j) {
                const int kl = mt * 16 + 4 * g + j;
                float s = st[mt][j] + Ms[kl];
                if (diag && (kb0 + kl > q_glob)) s = NEGINF;
                sv[mt * 4 + j] = s;
            }
        }

        float rmax = sv[0];
        #pragma unroll
        for (int i = 1; i < 16; ++i) rmax = fmaxf(rmax, sv[i]);
        rmax = fmaxf(rmax, __shfl_xor(rmax, 16));
        rmax = fmaxf(rmax, __shfl_xor(rmax, 32));
        const float mnew = fmaxf(mrun, rmax);
        const float cf = __expf(mrun - mnew);
        float p[16], psum = 0.f;
        #pragma unroll
        for (int i = 0; i < 16; ++i) { p[i] = __expf(sv[i] - mnew); psum += p[i]; }
        psum += __shfl_xor(psum, 16);
        psum += __shfl_xor(psum, 32);
        lrun = lrun * cf + psum;
        mrun = mnew;

        float cj[4];
        #pragma unroll
        for (int j = 0; j < 4; ++j) cj[j] = __shfl(cf, 20 * g + j);
        #pragma unroll
        for (int nt = 0; nt < 4; ++nt)
            #pragma unroll
            for (int j = 0; j < 4; ++j) oacc[nt][j] *= cj[j];

        short8 pa[2];
        #pragma unroll
        for (int ks = 0; ks < 2; ++ks)
            #pragma unroll
            for (int i = 0; i < 8; ++i)
                pa[ks][i] = (short)f2bf(p[(2*ks + (i>>2))*4 + (i&3)]);

        #pragma unroll
        for (int nt = 0; nt < 4; ++nt) {
            const int d = 16 * nt + lm;
            const int xz = (((d & 7) ^ ((d >> 3) & 7)) & 7) << 4;
            const char* vb = (const char*)Vt + d * 128;
            #pragma unroll
            for (int ks = 0; ks < 2; ++ks) {
                union { short8 s; uintx2 u[2]; } vu;
                vu.u[0] = *(const uintx2*)(vb + ((64*ks + 8*g)      ^ xz));
                vu.u[1] = *(const uintx2*)(vb + ((64*ks + 8*g + 32) ^ xz));
                oacc[nt] = mfma16(pa[ks], vu.s, oacc[nt]);
            }
        }
        __syncthreads();
    }

    const float inv = 1.0f / lrun;
    #pragma unroll
    for (int j = 0; j < 4; ++j) {
        const float invj = __shfl(inv, 20 * g + j);
        const int row = qb * 128 + w * 16 + 4 * g + j;
        float* dst = og + (((size_t)b * S_LEN + row) * NHEAD + h) * DHEAD + lm;
        #pragma unroll
        for (int nt = 0; nt < 4; ++nt) dst[nt * 16] = oacc[nt][j] * invj;
    }
}

extern "C" void kernel_launch(void* const* d_in, const int* in_sizes, int n_in,
                              void* d_out, int out_size, void* d_ws, size_t ws_size,
                              hipStream_t stream)
{
    const float* q = (const float*)d_in[0];
    const float* k = (const float*)d_in[1];
    const float* v = (const float*)d_in[2];
    const int*   m = (const int*)d_in[3];
    float* out = (float*)d_out;
    (void)in_sizes; (void)n_in; (void)out_size;
    if (ws_size >= WS_NEEDED) {
        prep_kernel<<<dim3(1024), dim3(256), 0, stream>>>(k, v, m, (char*)d_ws);
        fa3_main<<<dim3(768), dim3(512), 0, stream>>>(q, (char*)d_ws, out);
        fa3_combine<<<dim3(1024), dim3(256), 0, stream>>>((const char*)d_ws, out);
    } else {
        fa3_fallback<<<dim3(512), dim3(512), 0, stream>>>(q, k, v, m, out);
    }
}